// Round 1
// baseline (471.547 us; speedup 1.0000x reference)
//
#include <hip/hip_runtime.h>

// TopKActivation: per row, out = relu(x) masked to its top-128 values.
// One block per row. Exact 4x8-bit radix select on fp32 bit patterns in LDS.

constexpr int COLS = 8192;
constexpr int NT   = 256;            // threads per block (4 waves)
constexpr int EPT  = COLS / NT;      // 32 elements per thread
constexpr int V4PT = COLS / 4 / NT;  // 8 float4 per thread
constexpr int TOPK = 128;

__global__ __launch_bounds__(NT)
void topk_relu_kernel(const float* __restrict__ x, float* __restrict__ out) {
  __shared__ unsigned vals[COLS];        // relu'd values as raw bits (32 KiB)
  __shared__ unsigned whist[4 * 256];    // per-wave private histograms
  __shared__ unsigned hsc[256];          // scan buffer
  __shared__ unsigned sel_digit, sel_krem, sel_count;

  const int tid = threadIdx.x;
  const size_t row = blockIdx.x;

  // ---- stage: load row, relu via sign bit, store bits to LDS (coalesced) ----
  const uint4* __restrict__ xin = reinterpret_cast<const uint4*>(x + row * COLS);
  uint4* v4 = reinterpret_cast<uint4*>(vals);
#pragma unroll
  for (int it = 0; it < V4PT; ++it) {
    uint4 u = xin[it * NT + tid];
    u.x = (u.x >> 31) ? 0u : u.x;   // negative (or -0) -> 0; non-neg bits order as floats
    u.y = (u.y >> 31) ? 0u : u.y;
    u.z = (u.z >> 31) ? 0u : u.z;
    u.w = (u.w >> 31) ? 0u : u.w;
    v4[it * NT + tid] = u;
  }
  __syncthreads();

  // ---- exact radix select: find bit pattern of the TOPK-th largest ----
  unsigned prefix = 0u, maskhi = 0u, krem = TOPK;
  unsigned count_eq = 0u;
  bool allpos = false;  // fewer than TOPK nonzero elements -> keep all positives

  for (int shift = 24; shift >= 0; shift -= 8) {
    // clear per-wave histograms
#pragma unroll
    for (int i = 0; i < 4; ++i) whist[i * 256 + tid] = 0u;
    __syncthreads();

    unsigned* myh = &whist[(tid >> 6) * 256];
    for (int j = 0; j < EPT; ++j) {
      unsigned b = vals[j * NT + tid];              // stride-NT: conflict-free
      if (b != 0u && (b & maskhi) == prefix)        // skip zeros + prefix filter
        atomicAdd(&myh[(b >> shift) & 0xFFu], 1u);
    }
    __syncthreads();

    // reduce 4 private hists, then inclusive suffix scan (Hillis-Steele)
    unsigned hv = whist[tid] + whist[256 + tid] + whist[512 + tid] + whist[768 + tid];
    hsc[tid] = hv;
    __syncthreads();
#pragma unroll
    for (int off = 1; off < 256; off <<= 1) {
      unsigned v = hsc[tid] + ((tid + off < 256) ? hsc[tid + off] : 0u);
      __syncthreads();
      hsc[tid] = v;
      __syncthreads();
    }

    if (shift == 24 && hsc[0] < krem) {  // uniform branch: < TOPK positives in row
      allpos = true;
      break;
    }

    // pick digit d with  S[d+1] < krem <= S[d]
    unsigned Sd  = hsc[tid];
    unsigned Sd1 = (tid < 255) ? hsc[tid + 1] : 0u;
    if (Sd1 < krem && krem <= Sd) {
      sel_digit = (unsigned)tid;
      sel_krem  = krem - Sd1;     // still needed among elements with this digit
      sel_count = Sd - Sd1;       // elements with this digit (== hist[d])
    }
    __syncthreads();
    prefix  |= sel_digit << shift;
    maskhi  |= 0xFFu << shift;
    krem     = sel_krem;
    count_eq = sel_count;
    __syncthreads();  // protect sel_* reads before next pass rewrites them
  }

  const unsigned tbits = allpos ? 0u : prefix;

  // ---- rare exact tie-break: drop excess elements == tbits at highest indices ----
  if (!allpos && count_eq > krem) {
    unsigned cnt = 0;
    for (int j = 0; j < EPT; ++j) cnt += (vals[tid * EPT + j] == tbits) ? 1u : 0u;
    hsc[tid] = cnt;
    __syncthreads();
#pragma unroll
    for (int off = 1; off < 256; off <<= 1) {
      unsigned v = hsc[tid] + ((tid >= off) ? hsc[tid - off] : 0u);
      __syncthreads();
      hsc[tid] = v;
      __syncthreads();
    }
    unsigned excl = hsc[tid] - cnt;  // equals before my chunk (index order)
    unsigned r = 0;
    for (int j = 0; j < EPT; ++j) {
      unsigned idx = (unsigned)tid * EPT + j;
      if (vals[idx] == tbits) {
        if (excl + r >= krem) vals[idx] = 0u;  // dropped: lowest-index ones kept
        ++r;
      }
    }
    __syncthreads();
  }

  // ---- write: keep iff bits >= tbits (drops already zeroed); coalesced float4 ----
  float4* __restrict__ o4 = reinterpret_cast<float4*>(out + row * COLS);
#pragma unroll
  for (int it = 0; it < V4PT; ++it) {
    uint4 u = v4[it * NT + tid];
    float4 f;
    f.x = (u.x >= tbits) ? __uint_as_float(u.x) : 0.0f;
    f.y = (u.y >= tbits) ? __uint_as_float(u.y) : 0.0f;
    f.z = (u.z >= tbits) ? __uint_as_float(u.z) : 0.0f;
    f.w = (u.w >= tbits) ? __uint_as_float(u.w) : 0.0f;
    o4[it * NT + tid] = f;
  }
}

extern "C" void kernel_launch(void* const* d_in, const int* in_sizes, int n_in,
                              void* d_out, int out_size, void* d_ws, size_t ws_size,
                              hipStream_t stream) {
  const float* x = (const float*)d_in[0];
  float* out = (float*)d_out;
  const int rows = in_sizes[0] / COLS;  // 8192
  topk_relu_kernel<<<rows, NT, 0, stream>>>(x, out);
}

// Round 2
// 450.937 us; speedup vs baseline: 1.0457x; 1.0457x over previous
//
#include <hip/hip_runtime.h>

// TopKActivation: per row, out = relu(x) masked to its top-128 values.
// R2: register-resident values; 3-pass (11/10/10-bit) radix select; padded
// histogram (addr = d + d>>3 -> stride-9 chunks, <=2-way bank alias = free);
// hierarchical suffix scan (4 barriers/pass); exact lowest-index tie-break
// via storage-free binary search; nontemporal vectorized output stores.

constexpr int COLS = 8192;
constexpr int NT   = 256;           // 4 waves
constexpr int V4   = COLS / 4 / NT; // 8 uint4 per thread (32 values)
constexpr int TOPK = 128;
constexpr int HPAD = 2048 + 2048 / 8;  // 2304 words = 9 KiB

typedef float v4f __attribute__((ext_vector_type(4)));

__device__ __forceinline__ unsigned hpad(unsigned d) { return d + (d >> 3); }

// One radix pass over register-resident values. Returns (via refs) the
// selected digit, remaining k within that digit, count at that digit, and
// (FIRST only) the total number of nonzero elements.
template<int SHIFT, int NB, bool FIRST>
__device__ __forceinline__ void radix_pass(
    const uint4 (&va)[V4], unsigned pref, unsigned krem,
    unsigned* hist, unsigned* wtot, unsigned* bc,
    int tid, int lane, int wv,
    unsigned& sel, unsigned& krem_out, unsigned& cnt_out, unsigned& total_out)
{
  constexpr int LB = (NB == 2048) ? 11 : 10;
  constexpr int BP = NB / NT;  // bins per thread: 8 (pass1) or 4 (pass2/3)

  for (int i = tid; i < NB + NB / 8; i += NT) hist[i] = 0u;
  __syncthreads();

  // histogram from registers; zeros skipped, prefix-filtered after pass 1
#pragma unroll
  for (int it = 0; it < V4; ++it) {
    unsigned b[4] = {va[it].x, va[it].y, va[it].z, va[it].w};
#pragma unroll
    for (int c = 0; c < 4; ++c) {
      unsigned v = b[c];
      bool ok = FIRST ? (v != 0u) : (v != 0u && (v >> (SHIFT + LB)) == pref);
      if (ok) atomicAdd(&hist[hpad((v >> SHIFT) & (NB - 1))], 1u);
    }
  }
  __syncthreads();

  // hierarchical inclusive suffix scan: thread-local BP bins -> wave shfl -> cross-wave
  unsigned h[BP], tot = 0;
#pragma unroll
  for (int i = 0; i < BP; ++i) { h[i] = hist[hpad((unsigned)(tid * BP + i))]; tot += h[i]; }

  unsigned s = tot;
#pragma unroll
  for (int off = 1; off < 64; off <<= 1) {
    unsigned o = __shfl_down(s, off);
    if (lane + off < 64) s += o;
  }
  if (lane == 0) wtot[wv] = s;  // wave total
  __syncthreads();

  unsigned after = 0;
#pragma unroll
  for (int w = 0; w < 4; ++w) if (w > wv) after += wtot[w];
  const unsigned S_after = (s - tot) + after;  // suffix strictly after this thread

  if (FIRST && tid == 0) bc[3] = s + after;    // total nonzero count (thread 0)

  // unique crossing thread walks its bins high->low
  if (S_after < krem && krem <= S_after + tot) {
    unsigned S = S_after;
#pragma unroll
    for (int i = BP - 1; i >= 0; --i) {
      unsigned Sn = S + h[i];
      if (S < krem && krem <= Sn) {
        bc[0] = (unsigned)(tid * BP + i);
        bc[1] = krem - S;     // still needed among elements with this digit
        bc[2] = h[i];         // elements with this digit
      }
      S = Sn;
    }
  }
  __syncthreads();
  sel      = bc[0];
  krem_out = bc[1];
  cnt_out  = bc[2];
  total_out = FIRST ? bc[3] : 0u;
  // no trailing barrier needed: next pass clears hist (not bc/wtot) and
  // syncs twice before rewriting bc/wtot.
}

__global__ __launch_bounds__(NT, 4)
void topk_relu_kernel(const float* __restrict__ x, float* __restrict__ out)
{
  __shared__ unsigned hist[HPAD];
  __shared__ unsigned wtot[4];
  __shared__ unsigned bc[4];
  __shared__ unsigned tiectr;

  const int tid = threadIdx.x, lane = tid & 63, wv = tid >> 6;
  const size_t row = blockIdx.x;

  // ---- load + relu into registers (coalesced uint4) ----
  uint4 va[V4];
  const uint4* __restrict__ xin = reinterpret_cast<const uint4*>(x + row * COLS);
#pragma unroll
  for (int it = 0; it < V4; ++it) {
    uint4 u = xin[it * NT + tid];
    u.x = (u.x & 0x80000000u) ? 0u : u.x;  // relu: non-neg fp32 bits order as floats
    u.y = (u.y & 0x80000000u) ? 0u : u.y;
    u.z = (u.z & 0x80000000u) ? 0u : u.z;
    u.w = (u.w & 0x80000000u) ? 0u : u.w;
    va[it] = u;
  }

  unsigned sel, krem = TOPK, cnt = 0, total = 0;
  unsigned tbits = 0u;      // threshold bit pattern (0 if < TOPK positives)
  unsigned C = COLS;        // index cutoff for elements == tbits (tie-break)

  // pass 1: bits 30:20 (sign is always 0 after relu)
  radix_pass<20, 2048, true>(va, 0u, krem, hist, wtot, bc, tid, lane, wv,
                             sel, krem, cnt, total);
  if (total >= TOPK) {  // uniform branch; else keep all positives (tbits=0)
    unsigned pref = sel;
    radix_pass<10, 1024, false>(va, pref, krem, hist, wtot, bc, tid, lane, wv,
                                sel, krem, cnt, total);
    pref = (pref << 10) | sel;
    radix_pass<0, 1024, false>(va, pref, krem, hist, wtot, bc, tid, lane, wv,
                               sel, krem, cnt, total);
    tbits = (pref << 10) | sel;

    // ---- rare exact tie at threshold: keep the krem lowest-indexed equals.
    // Binary search smallest C with |{idx < C : v == tbits}| == krem.
    if (cnt > krem) {
      unsigned eq = 0u;
#pragma unroll
      for (int it = 0; it < V4; ++it) {
        if (va[it].x == tbits) eq |= 1u << (it * 4 + 0);
        if (va[it].y == tbits) eq |= 1u << (it * 4 + 1);
        if (va[it].z == tbits) eq |= 1u << (it * 4 + 2);
        if (va[it].w == tbits) eq |= 1u << (it * 4 + 3);
      }
      unsigned lo = 0, hi = COLS;
      while (lo < hi) {              // uniform loop (lo/hi from shared ctr)
        unsigned mid = (lo + hi) >> 1;
        if (tid == 0) tiectr = 0u;
        __syncthreads();
        if (eq) {
          unsigned c = 0;
#pragma unroll
          for (int it = 0; it < V4; ++it)
#pragma unroll
            for (int cc = 0; cc < 4; ++cc)
              if (((eq >> (it * 4 + cc)) & 1u) &&
                  (unsigned)((it * NT + tid) * 4 + cc) < mid) ++c;
          if (c) atomicAdd(&tiectr, c);
        }
        __syncthreads();
        unsigned cm = tiectr;
        if (cm >= krem) hi = mid; else lo = mid + 1;
        __syncthreads();
      }
      C = lo;
    }
  }

  // ---- write from registers; nontemporal (write-once output, spare L3) ----
  v4f* o4 = reinterpret_cast<v4f*>(out + row * COLS);
#pragma unroll
  for (int it = 0; it < V4; ++it) {
    unsigned base = (unsigned)(it * NT + tid) * 4u;
    uint4 u = va[it];
    v4f f;
    f.x = (u.x > tbits || (u.x == tbits && base + 0 < C)) ? __uint_as_float(u.x) : 0.0f;
    f.y = (u.y > tbits || (u.y == tbits && base + 1 < C)) ? __uint_as_float(u.y) : 0.0f;
    f.z = (u.z > tbits || (u.z == tbits && base + 2 < C)) ? __uint_as_float(u.z) : 0.0f;
    f.w = (u.w > tbits || (u.w == tbits && base + 3 < C)) ? __uint_as_float(u.w) : 0.0f;
    __builtin_nontemporal_store(f, &o4[it * NT + tid]);
  }
}

extern "C" void kernel_launch(void* const* d_in, const int* in_sizes, int n_in,
                              void* d_out, int out_size, void* d_ws, size_t ws_size,
                              hipStream_t stream) {
  const float* x = (const float*)d_in[0];
  float* out = (float*)d_out;
  const int rows = in_sizes[0] / COLS;  // 8192
  topk_relu_kernel<<<rows, NT, 0, stream>>>(x, out);
}